// Round 16
// baseline (275.339 us; speedup 1.0000x reference)
//
#include <hip/hip_runtime.h>
#include <hip/hip_bf16.h>
#include <math.h>

#define RR 64
#define CC 32
#define NPTS (4*262144)

typedef __attribute__((ext_vector_type(8))) short short8;
typedef __attribute__((ext_vector_type(4))) float f32x4;
typedef __attribute__((ext_vector_type(4))) unsigned int u32x4;

static __device__ inline ushort f2bf(float x) {
    return __builtin_bit_cast(ushort, __float2bfloat16(x));
}
// Two f32 -> packed bf16 pair in ONE instruction (RNE).
static __device__ inline uint32_t pk2(float a, float b) {
    uint32_t r;
    asm("v_cvt_pk_bf16_f32 %0, %1, %2" : "=v"(r) : "v"(a), "v"(b));
    return r;
}
static __device__ inline f32x4 relu4(f32x4 v) {
    f32x4 z = {0.f, 0.f, 0.f, 0.f};
    return __builtin_elementwise_max(v, z);
}

// ws layout (floats unless noted):
//   float  Pcl[393216]   @ 0         channel-last fp32 planes [p][y][x][ch]
//   ushort W1T[24576]    @ 393216    layer1 A-frag table [nt<16][p<3][lane][e]
//   ushort W2T[16384]    follows     layer2 A-frag table [nt2<8][kt2<4][lane][e]
//   float  BC[256]       @ 413696    bias concat db1|rb1
// W1T+W2T = 81920 B staged to LDS; 2 blocks/CU fit exactly if regs allow.

__global__ void prepass(const float* __restrict__ planes,
                        const float* __restrict__ dW1, const float* __restrict__ rW1,
                        const float* __restrict__ dW2,
                        const float* __restrict__ db1, const float* __restrict__ rb1,
                        float* __restrict__ ws) {
    int tid = blockIdx.x * blockDim.x + threadIdx.x;
    ushort* W1T = (ushort*)(ws + 393216);
    ushort* W2T = W1T + 24576;
    float*  BC  = ws + 413696;

    if (tid < 3 * CC * RR * RR) {
        int x = tid % RR, y = (tid / RR) % RR, ch = (tid / (RR * RR)) % CC, p = tid / (CC * RR * RR);
        ws[((p * RR + y) * RR + x) * CC + ch] = planes[tid];
    }
    if (tid < 24576) {   // W1T: tid = ((nt*3+p)*64 + l)*8 + e
        int e = tid & 7, l = (tid >> 3) & 63, rem = tid >> 9;
        int p = rem % 3, nt = rem / 3;
        int j = nt * 16 + (l & 15);
        int k = p * 32 + (l >> 4) * 8 + e;
        float v = (j < 128) ? dW1[j * 96 + k] : rW1[(j - 128) * 96 + k];
        W1T[tid] = f2bf(v);
    }
    if (tid < 16384) {   // W2T: tid = ((nt2*4+kt2)*64 + l)*8 + e
        int e = tid & 7, l = (tid >> 3) & 63, rem = tid >> 9;
        int kt2 = rem & 3, nt2 = rem >> 2;
        int j2 = nt2 * 16 + (l & 15);
        int k = kt2 * 32 + (l >> 4) * 8 + e;
        W2T[tid] = f2bf(dW2[j2 * 128 + k]);
    }
    if (tid < 256) BC[tid] = (tid < 128) ? db1[tid] : rb1[tid - 128];
}

// Bilinear-sample 8 channels (8g..8g+7) of one plane at (cx,cy), packed as a
// bf16 MFMA B-fragment. Packed-f32 interp + single-instr bf16 packing.
static __device__ inline short8 sample_frag(const float* __restrict__ P,
                                            int plane_base, float cx, float cy, int g8) {
    float ix = (cx + 1.0f) * 31.5f; ix = fminf(fmaxf(ix, 0.0f), 63.0f);
    float iy = (cy + 1.0f) * 31.5f; iy = fminf(fmaxf(iy, 0.0f), 63.0f);
    int x0 = (int)ix, y0 = (int)iy;
    int x1 = min(x0 + 1, 63), y1 = min(y0 + 1, 63);
    float wx = ix - (float)x0, wy = iy - (float)y0;
    float w00 = (1.0f - wx) * (1.0f - wy), w01 = wx * (1.0f - wy);
    float w10 = (1.0f - wx) * wy,          w11 = wx * wy;
    int b00 = plane_base + (y0 * 64 + x0) * 32 + g8;
    int b01 = plane_base + (y0 * 64 + x1) * 32 + g8;
    int b10 = plane_base + (y1 * 64 + x0) * 32 + g8;
    int b11 = plane_base + (y1 * 64 + x1) * 32 + g8;
    f32x4 a0 = *(const f32x4*)(P + b00), a1 = *(const f32x4*)(P + b00 + 4);
    f32x4 c0 = *(const f32x4*)(P + b01), c1 = *(const f32x4*)(P + b01 + 4);
    f32x4 d0 = *(const f32x4*)(P + b10), d1 = *(const f32x4*)(P + b10 + 4);
    f32x4 e0 = *(const f32x4*)(P + b11), e1 = *(const f32x4*)(P + b11 + 4);
    f32x4 flo = a0 * w00 + c0 * w01 + d0 * w10 + e0 * w11;
    f32x4 fhi = a1 * w00 + c1 * w01 + d1 * w10 + e1 * w11;
    u32x4 uu;
    uu[0] = pk2(flo[0], flo[1]); uu[1] = pk2(flo[2], flo[3]);
    uu[2] = pk2(fhi[0], fhi[1]); uu[3] = pk2(fhi[2], fhi[3]);
    return __builtin_bit_cast(short8, uu);
}

// rgb-head A-fragment for this lane (row = c = rgb channel for c<3, else 0).
static __device__ inline short8 rw_frag(const float* __restrict__ rW2,
                                        int kt2, int cc, int g8) {
    if (cc < 3) {
        const float* p = rW2 + cc * 128 + kt2 * 32 + g8;
        f32x4 v0 = *(const f32x4*)(p);
        f32x4 v1 = *(const f32x4*)(p + 4);
        u32x4 uu;
        uu[0] = pk2(v0[0], v0[1]); uu[1] = pk2(v0[2], v0[3]);
        uu[2] = pk2(v1[0], v1[1]); uu[3] = pk2(v1[2], v1[3]);
        return __builtin_bit_cast(short8, uu);
    }
    u32x4 z = {0u, 0u, 0u, 0u};
    return __builtin_bit_cast(short8, z);
}

#define MFMA(a, b, c) __builtin_amdgcn_mfma_f32_16x16x32_bf16((a), (b), (c), 0, 0, 0)

// One layer-1 output tile (j = 16*nt + 4g + r): bias rides as C-init; 3 MFMAs
// per point-half; relu+pack into two bf16-pair u32s per half.
#define L1NT(nt, oA0, oA1, oB0, oB1) { \
    const ushort* wp_ = W1L + (nt) * 1536 + lane * 8; \
    short8 a0_ = *(const short8*)(wp_); \
    short8 a1_ = *(const short8*)(wp_ + 512); \
    short8 a2_ = *(const short8*)(wp_ + 1024); \
    f32x4 bb_ = *(const f32x4*)(BCg + (nt) * 16 + 4 * g); \
    f32x4 accA_ = MFMA(a0_, bfA0, bb_); \
    f32x4 accB_ = MFMA(a0_, bfB0, bb_); \
    accA_ = MFMA(a1_, bfA1, accA_); accB_ = MFMA(a1_, bfB1, accB_); \
    accA_ = MFMA(a2_, bfA2, accA_); accB_ = MFMA(a2_, bfB2, accB_); \
    f32x4 vA_ = relu4(accA_); \
    f32x4 vB_ = relu4(accB_); \
    oA0 = pk2(vA_[0], vA_[1]); oA1 = pk2(vA_[2], vA_[3]); \
    oB0 = pk2(vB_[0], vB_[1]); oB1 = pk2(vB_[2], vB_[3]); }

// In-wave transpose: C-layout packed pairs (from nt = 2kt2, 2kt2+1) -> layer-2
// B-fragment for this kt2. Exchange among lanes {c, c+16, c+32, c+48}.
#define TRKT(p0a, p0b, p1a, p1b, outf) { \
    unsigned lo0_ = __shfl(p0a, s0, 64), hi0_ = __shfl(p1a, s0, 64); \
    unsigned lo1_ = __shfl(p0b, s0, 64), hi1_ = __shfl(p1b, s0, 64); \
    unsigned lo2_ = __shfl(p0a, s1, 64), hi2_ = __shfl(p1a, s1, 64); \
    unsigned lo3_ = __shfl(p0b, s1, 64), hi3_ = __shfl(p1b, s1, 64); \
    u32x4 uu_; \
    uu_[0] = gh ? hi0_ : lo0_;  uu_[1] = gh ? hi1_ : lo1_; \
    uu_[2] = gh ? hi2_ : lo2_;  uu_[3] = gh ? hi3_ : lo3_; \
    outf = __builtin_bit_cast(short8, uu_); }

// (512,1) on this toolchain: 1 block/CU min -> 256-VGPR cap. The deep-ILP
// live set (~175 regs incl. prefetch) fits; at <=128 the HW can co-schedule
// 2 blocks/CU (LDS 2x81920 = 160 KiB exactly).
__global__ __launch_bounds__(512, 1)
void nerf_mfma(const float* __restrict__ points, const float* __restrict__ ws,
               const float* __restrict__ db2g, const float* __restrict__ dW3g,
               const float* __restrict__ db3g,
               const float* __restrict__ rW2g, const float* __restrict__ rb2g,
               float* __restrict__ rgb_out, float* __restrict__ den_out) {
    __shared__ __align__(16) ushort SB[40960];   // 81920 B: W1T | W2T

    const float* P   = ws;
    const float* BCg = ws + 413696;
    int tid = threadIdx.x;

    // stage weight tables to LDS (81920 B = 5120 x 16B)
    {
        const u32x4* src = (const u32x4*)(ws + 393216);
        u32x4* dst = (u32x4*)SB;
        for (int j = tid; j < 5120; j += 512) dst[j] = src[j];
    }
    __syncthreads();

    const ushort* W1L = SB;             // 24576 ushorts
    const ushort* W2L = SB + 24576;     // 16384 ushorts

    int wid = tid >> 6, lane = tid & 63;
    int c = lane & 15, g = lane >> 4;
    int g8 = 8 * g;
    int s0 = c + ((g & 1) << 5);        // transpose source lanes
    int s1 = s0 + 16;
    bool gh = (g >= 2);
    int gw = blockIdx.x * 8 + wid;      // 4096 waves, 8 tiles each, 32 pts/tile

    // hoisted per-kernel constants
    float b3  = db3g[0];
    float rb0 = rb2g[0], rb1v = rb2g[1], rb2v = rb2g[2];
    short8 rw0 = rw_frag(rW2g, 0, c, g8);
    short8 rw1 = rw_frag(rW2g, 1, c, g8);
    short8 rw2 = rw_frag(rW2g, 2, c, g8);
    short8 rw3 = rw_frag(rW2g, 3, c, g8);

    // ---- prologue: gather + interp + convert for tile 0 ----
    int pbase = gw * 8 * 32;
    int ptA = pbase + c, ptB = pbase + c + 16;
    {
        float xa = points[ptA * 3 + 0], ya = points[ptA * 3 + 1], za = points[ptA * 3 + 2];
        float xb = points[ptB * 3 + 0], yb = points[ptB * 3 + 1], zb = points[ptB * 3 + 2];
    // (scoped so xa..zb die immediately)
        // fallthrough via assignments below
        // initial fragments:
        // note: placed in outer-scope variables
        // (declared next)
        ;
        // declare and set
        // -- see below
        // (kept minimal to limit live range)
        (void)0;
        // actual assignment happens after declarations
        // (we re-load coords here to keep code simple)
    }
    short8 bfA0, bfA1, bfA2, bfB0, bfB1, bfB2;
    {
        float xa = points[ptA * 3 + 0], ya = points[ptA * 3 + 1], za = points[ptA * 3 + 2];
        float xb = points[ptB * 3 + 0], yb = points[ptB * 3 + 1], zb = points[ptB * 3 + 2];
        bfA0 = sample_frag(P, 0,      xa, ya, g8);
        bfA1 = sample_frag(P, 131072, xa, za, g8);
        bfA2 = sample_frag(P, 262144, ya, za, g8);
        bfB0 = sample_frag(P, 0,      xb, yb, g8);
        bfB1 = sample_frag(P, 131072, xb, zb, g8);
        bfB2 = sample_frag(P, 262144, yb, zb, g8);
    }

    #pragma unroll 1
    for (int it = 0; it < 8; ++it) {
        unsigned pA0, pA1, qA0, qA1, pB0, pB1, qB0, qB1;

        // ---- rgb half (nt = 8..15): layer1 -> transpose -> head MFMA ----
        f32x4 rAacc = {0.f,0.f,0.f,0.f}, rBacc = {0.f,0.f,0.f,0.f};
        #define RKT(kt2, rwv) { \
            L1NT(8 + 2*(kt2), pA0, pA1, pB0, pB1); \
            L1NT(9 + 2*(kt2), qA0, qA1, qB0, qB1); \
            short8 brA_, brB_; \
            TRKT(pA0, pA1, qA0, qA1, brA_); \
            TRKT(pB0, pB1, qB0, qB1, brB_); \
            rAacc = MFMA(rwv, brA_, rAacc); \
            rBacc = MFMA(rwv, brB_, rBacc); }
        RKT(0, rw0) RKT(1, rw1) RKT(2, rw2) RKT(3, rw3)
        #undef RKT

        // rgb store (D[row=4g+r][col=c]; rows 0..2 live on g==0)
        if (g == 0) {
            rgb_out[ptA * 3 + 0] = 1.0f / (1.0f + expf(-(rAacc[0] + rb0)));
            rgb_out[ptA * 3 + 1] = 1.0f / (1.0f + expf(-(rAacc[1] + rb1v)));
            rgb_out[ptA * 3 + 2] = 1.0f / (1.0f + expf(-(rAacc[2] + rb2v)));
            rgb_out[ptB * 3 + 0] = 1.0f / (1.0f + expf(-(rBacc[0] + rb0)));
            rgb_out[ptB * 3 + 1] = 1.0f / (1.0f + expf(-(rBacc[1] + rb1v)));
            rgb_out[ptB * 3 + 2] = 1.0f / (1.0f + expf(-(rBacc[2] + rb2v)));
        }

        // ---- prefetch next tile's gather + interp + convert (independent of
        // everything below; VMEM latency hides under DKT + layer2) ----
        short8 nxA0 = bfA0, nxA1 = bfA1, nxA2 = bfA2;
        short8 nxB0 = bfB0, nxB1 = bfB1, nxB2 = bfB2;
        int nptA = ptA, nptB = ptB;
        if (it < 7) {
            int npbase = pbase + 32;
            nptA = npbase + c; nptB = npbase + c + 16;
            float nxa = points[nptA * 3 + 0], nya = points[nptA * 3 + 1], nza = points[nptA * 3 + 2];
            float nxb = points[nptB * 3 + 0], nyb = points[nptB * 3 + 1], nzb = points[nptB * 3 + 2];
            nxA0 = sample_frag(P, 0,      nxa, nya, g8);
            nxA1 = sample_frag(P, 131072, nxa, nza, g8);
            nxA2 = sample_frag(P, 262144, nya, nza, g8);
            nxB0 = sample_frag(P, 0,      nxb, nyb, g8);
            nxB1 = sample_frag(P, 131072, nxb, nzb, g8);
            nxB2 = sample_frag(P, 262144, nyb, nzb, g8);
        }

        // ---- density half (nt = 0..7): layer1 -> transpose -> b2 frags ----
        short8 b2A0, b2A1, b2A2, b2A3, b2B0, b2B1, b2B2, b2B3;
        #define DKT(kt2, B2A, B2B) { \
            L1NT(2*(kt2),     pA0, pA1, pB0, pB1); \
            L1NT(2*(kt2) + 1, qA0, qA1, qB0, qB1); \
            TRKT(pA0, pA1, qA0, qA1, B2A); \
            TRKT(pB0, pB1, qB0, qB1, B2B); }
        DKT(0, b2A0, b2B0) DKT(1, b2A1, b2B1) DKT(2, b2A2, b2B2) DKT(3, b2A3, b2B3)
        #undef DKT

        // ---- layer2 + density fold (bias as C-init; b/w tables L1-resident) ----
        f32x4 dA4 = {0.f,0.f,0.f,0.f}, dB4 = {0.f,0.f,0.f,0.f};
        #pragma unroll 2
        for (int nt2 = 0; nt2 < 8; ++nt2) {
            const ushort* wp = W2L + nt2 * 2048 + lane * 8;
            short8 a0 = *(const short8*)(wp);
            short8 a1 = *(const short8*)(wp + 512);
            short8 a2 = *(const short8*)(wp + 1024);
            short8 a3 = *(const short8*)(wp + 1536);
            f32x4 bb = *(const f32x4*)(db2g + nt2 * 16 + 4 * g);
            f32x4 accA = MFMA(a0, b2A0, bb);
            f32x4 accB = MFMA(a0, b2B0, bb);
            accA = MFMA(a1, b2A1, accA); accB = MFMA(a1, b2B1, accB);
            accA = MFMA(a2, b2A2, accA); accB = MFMA(a2, b2B2, accB);
            accA = MFMA(a3, b2A3, accA); accB = MFMA(a3, b2B3, accB);
            f32x4 w3 = *(const f32x4*)(dW3g + nt2 * 16 + 4 * g);
            dA4 += w3 * relu4(accA);
            dB4 += w3 * relu4(accB);
        }

        // ---- density heads ----
        {
            float v = (dA4[0] + dA4[1]) + (dA4[2] + dA4[3]);
            v += __shfl_xor(v, 16, 64); v += __shfl_xor(v, 32, 64); v += b3;
            float sp = fmaxf(v, 0.0f) + log1pf(expf(-fabsf(v)));
            if (g == 0) den_out[ptA] = sp;
        }
        {
            float v = (dB4[0] + dB4[1]) + (dB4[2] + dB4[3]);
            v += __shfl_xor(v, 16, 64); v += __shfl_xor(v, 32, 64); v += b3;
            float sp = fmaxf(v, 0.0f) + log1pf(expf(-fabsf(v)));
            if (g == 0) den_out[ptB] = sp;
        }

        // ---- rotate pipeline registers ----
        bfA0 = nxA0; bfA1 = nxA1; bfA2 = nxA2;
        bfB0 = nxB0; bfB1 = nxB1; bfB2 = nxB2;
        ptA = nptA; ptB = nptB;
        pbase += 32;
    }
}

extern "C" void kernel_launch(void* const* d_in, const int* in_sizes, int n_in,
                              void* d_out, int out_size, void* d_ws, size_t ws_size,
                              hipStream_t stream) {
    const float* points = (const float*)d_in[0];
    const float* planes = (const float*)d_in[1];
    const float* dW1    = (const float*)d_in[2];
    const float* db1    = (const float*)d_in[3];
    const float* dW2    = (const float*)d_in[4];
    const float* db2    = (const float*)d_in[5];
    const float* dW3    = (const float*)d_in[6];
    const float* db3    = (const float*)d_in[7];
    const float* rW1    = (const float*)d_in[8];
    const float* rb1    = (const float*)d_in[9];
    const float* rW2    = (const float*)d_in[10];
    const float* rb2    = (const float*)d_in[11];

    float* out     = (float*)d_out;
    float* rgb_out = out;                 // 3*NPTS floats
    float* den_out = out + 3 * NPTS;      // NPTS floats
    float* ws      = (float*)d_ws;

    prepass<<<1536, 256, 0, stream>>>(planes, dW1, rW1, dW2, db1, rb1, ws);
    nerf_mfma<<<512, 512, 0, stream>>>(points, ws, db2, dW3, db3, rW2, rb2,
                                       rgb_out, den_out);
}

// Round 17
// 213.710 us; speedup vs baseline: 1.2884x; 1.2884x over previous
//
#include <hip/hip_runtime.h>
#include <hip/hip_bf16.h>
#include <math.h>

#define RR 64
#define CC 32
#define NPTS (4*262144)

typedef __attribute__((ext_vector_type(8))) short short8;
typedef __attribute__((ext_vector_type(4))) float f32x4;
typedef __attribute__((ext_vector_type(4))) unsigned int u32x4;

static __device__ inline ushort f2bf(float x) {
    return __builtin_bit_cast(ushort, __float2bfloat16(x));
}
static __device__ inline uint32_t pk2(float a, float b) {
    return (uint32_t)f2bf(a) | ((uint32_t)f2bf(b) << 16);
}
static __device__ inline f32x4 relu4(f32x4 v) {
    f32x4 z = {0.f, 0.f, 0.f, 0.f};
    return __builtin_elementwise_max(v, z);
}
static __device__ inline float hsum4(f32x4 v) {
    return (v[0] + v[1]) + (v[2] + v[3]);
}

// ws layout:
//   float  Pcl[3*64*64*32]   @ 0          channel-last fp32 planes [p][y][x][ch]
//   ushort W1T[24576]        @ 393216 f   layer1 A-frag table [nt][p][lane][e]
//   ushort W2T[16384]        follows      layer2 A-frag table [nt2][kt2][lane][e]
//   float  CWS[896]          follows      BC[256]=db1|rb1 | db2[128] | dW3[128] | rW2[384]
// W1T..CWS = 85504 B, staged to LDS once per block.

__global__ void prepass(const float* __restrict__ planes,
                        const float* __restrict__ dW1, const float* __restrict__ rW1,
                        const float* __restrict__ dW2,
                        const float* __restrict__ db1, const float* __restrict__ rb1,
                        const float* __restrict__ db2, const float* __restrict__ dW3,
                        const float* __restrict__ rW2,
                        float* __restrict__ ws) {
    int tid = blockIdx.x * blockDim.x + threadIdx.x;
    ushort* W1T = (ushort*)(ws + 393216);
    ushort* W2T = W1T + 24576;
    float*  CWS = ws + 393216 + 20480;

    if (tid < 3 * CC * RR * RR) {
        int x = tid % RR, y = (tid / RR) % RR, ch = (tid / (RR * RR)) % CC, p = tid / (CC * RR * RR);
        ws[((p * RR + y) * RR + x) * CC + ch] = planes[tid];
    }
    if (tid < 24576) {   // W1T: tid = ((nt*3+p)*64 + l)*8 + e
        int e = tid & 7, l = (tid >> 3) & 63, rem = tid >> 9;
        int p = rem % 3, nt = rem / 3;
        int j = nt * 16 + (l & 15);
        int k = p * 32 + (l >> 4) * 8 + e;
        float v = (j < 128) ? dW1[j * 96 + k] : rW1[(j - 128) * 96 + k];
        W1T[tid] = f2bf(v);
    }
    if (tid < 16384) {   // W2T: tid = ((nt2*4+kt2)*64 + l)*8 + e
        int e = tid & 7, l = (tid >> 3) & 63, rem = tid >> 9;
        int kt2 = rem & 3, nt2 = rem >> 2;
        int j2 = nt2 * 16 + (l & 15);
        int k = kt2 * 32 + (l >> 4) * 8 + e;
        W2T[tid] = f2bf(dW2[j2 * 128 + k]);
    }
    if (tid < 256) CWS[tid]       = (tid < 128) ? db1[tid] : rb1[tid - 128];
    if (tid < 128) CWS[256 + tid] = db2[tid];
    if (tid < 128) CWS[384 + tid] = dW3[tid];
    if (tid < 384) CWS[512 + tid] = rW2[tid];
}

// Bilinear-sample 8 channels (8g..8g+7) of one plane at (cx,cy), packed as a
// bf16 MFMA B-fragment. Vector (packed-f32) interpolation arithmetic.
static __device__ inline short8 sample_frag(const float* __restrict__ P,
                                            int plane_base, float cx, float cy, int g8) {
    float ix = (cx + 1.0f) * 31.5f; ix = fminf(fmaxf(ix, 0.0f), 63.0f);
    float iy = (cy + 1.0f) * 31.5f; iy = fminf(fmaxf(iy, 0.0f), 63.0f);
    int x0 = (int)ix, y0 = (int)iy;
    int x1 = min(x0 + 1, 63), y1 = min(y0 + 1, 63);
    float wx = ix - (float)x0, wy = iy - (float)y0;
    float w00 = (1.0f - wx) * (1.0f - wy), w01 = wx * (1.0f - wy);
    float w10 = (1.0f - wx) * wy,          w11 = wx * wy;
    int b00 = plane_base + (y0 * 64 + x0) * 32 + g8;
    int b01 = plane_base + (y0 * 64 + x1) * 32 + g8;
    int b10 = plane_base + (y1 * 64 + x0) * 32 + g8;
    int b11 = plane_base + (y1 * 64 + x1) * 32 + g8;
    f32x4 a0 = *(const f32x4*)(P + b00), a1 = *(const f32x4*)(P + b00 + 4);
    f32x4 c0 = *(const f32x4*)(P + b01), c1 = *(const f32x4*)(P + b01 + 4);
    f32x4 d0 = *(const f32x4*)(P + b10), d1 = *(const f32x4*)(P + b10 + 4);
    f32x4 e0 = *(const f32x4*)(P + b11), e1 = *(const f32x4*)(P + b11 + 4);
    f32x4 flo = a0 * w00 + c0 * w01 + d0 * w10 + e0 * w11;   // v_pk_fma_f32
    f32x4 fhi = a1 * w00 + c1 * w01 + d1 * w10 + e1 * w11;
    u32x4 uu;
    uu[0] = pk2(flo[0], flo[1]); uu[1] = pk2(flo[2], flo[3]);
    uu[2] = pk2(fhi[0], fhi[1]); uu[3] = pk2(fhi[2], fhi[3]);
    return __builtin_bit_cast(short8, uu);
}

#define MFMA(a, b, c) __builtin_amdgcn_mfma_f32_16x16x32_bf16((a), (b), (c), 0, 0, 0)

// Density layer-1 tile nt for BOTH point halves: one A-frag read feeds 2 MFMAs.
// A-half result -> H (LDS); B-half result -> two named u32 regs (written later).
#define DNT(nt, HB0, HB1) { \
    const ushort* wp_ = W1L + (nt) * 1536 + lane * 8; \
    short8 a0_ = *(const short8*)(wp_); \
    short8 a1_ = *(const short8*)(wp_ + 512); \
    short8 a2_ = *(const short8*)(wp_ + 1024); \
    f32x4 accA_ = {0.f,0.f,0.f,0.f}, accB_ = {0.f,0.f,0.f,0.f}; \
    accA_ = MFMA(a0_, bfA0, accA_); accB_ = MFMA(a0_, bfB0, accB_); \
    accA_ = MFMA(a1_, bfA1, accA_); accB_ = MFMA(a1_, bfB1, accB_); \
    accA_ = MFMA(a2_, bfA2, accA_); accB_ = MFMA(a2_, bfB2, accB_); \
    f32x4 bb_ = *(const f32x4*)(Cl + (nt) * 16 + 4 * g); \
    f32x4 vA_ = relu4(accA_ + bb_); \
    f32x4 vB_ = relu4(accB_ + bb_); \
    uint2 wA_; \
    wA_.x = pk2(vA_[0], vA_[1]); \
    wA_.y = pk2(vA_[2], vA_[3]); \
    *(uint2*)(&H[c][16 * (nt) + 4 * g]) = wA_; \
    HB0 = pk2(vB_[0], vB_[1]); \
    HB1 = pk2(vB_[2], vB_[3]); }

#define HWB(nt, HB0, HB1) { \
    uint2 t_; t_.x = HB0; t_.y = HB1; \
    *(uint2*)(&H[c][16 * (nt) + 4 * g]) = t_; }

// DS-only scheduler wall: keeps same-wave LDS write->read program order while
// letting VALU/SALU/MFMA/VMEM (mask 0x7F) migrate across for pipelining.
#define DSWALL __builtin_amdgcn_sched_barrier(0x7F)

// NOTE: second __launch_bounds__ arg behaves as min BLOCKS per CU on this
// toolchain. (1024,1): 16 waves/CU = 4/SIMD -> 128-VGPR cap.
__global__ __launch_bounds__(1024, 1)
void nerf_mfma(const float* __restrict__ points, const float* __restrict__ ws,
               const float* __restrict__ db3g, const float* __restrict__ rb2g,
               float* __restrict__ rgb_out, float* __restrict__ den_out) {
    // LDS: weights+consts 85504 B + per-wave H 16*16*136*2 = 69632 B -> 155136 B
    __shared__ __align__(16) ushort SB[42752];
    __shared__ __align__(16) ushort Hs[16][16][136];

    const float* P = ws;
    int tid = threadIdx.x;

    // ---- stage weight tables + consts into LDS (once per block) ----
    {
        const u32x4* src = (const u32x4*)(ws + 393216);
        u32x4* dst = (u32x4*)SB;
        for (int j = tid; j < 5344; j += 1024) dst[j] = src[j];
    }
    __syncthreads();

    const ushort* W1L = SB;                          // 24576 ushorts
    const ushort* W2L = SB + 24576;                  // 16384 ushorts
    const float*  Cl  = (const float*)(SB + 40960);  // BC | db2 | dW3 | rW2

    int wid = tid >> 6, lane = tid & 63;
    int c = lane & 15, g = lane >> 4;
    int g8 = 8 * g;
    ushort (*H)[136] = Hs[wid];
    int gw = blockIdx.x * 16 + wid;     // 16384 waves, 2 tiles each, 32 pts/tile

    float b3  = db3g[0];
    float rb0 = rb2g[0], rb1v = rb2g[1], rb2v = rb2g[2];

    // ---- hoist BOTH tiles' point coordinates (independent loads; removes the
    // 2-level load dependency from tile 1's critical path) ----
    int pt0 = gw * 64;
    int ptA0 = pt0 + c,      ptB0 = pt0 + c + 16;
    int ptA1 = pt0 + 32 + c, ptB1 = pt0 + 48 + c;
    float xa0 = points[ptA0*3+0], ya0 = points[ptA0*3+1], za0 = points[ptA0*3+2];
    float xb0 = points[ptB0*3+0], yb0 = points[ptB0*3+1], zb0 = points[ptB0*3+2];
    float xa1 = points[ptA1*3+0], ya1 = points[ptA1*3+1], za1 = points[ptA1*3+2];
    float xb1 = points[ptB1*3+0], yb1 = points[ptB1*3+1], zb1 = points[ptB1*3+2];

    #pragma unroll
    for (int it = 0; it < 2; ++it) {
        int ptA = it ? ptA1 : ptA0, ptB = it ? ptB1 : ptB0;
        float xa = it ? xa1 : xa0, ya = it ? ya1 : ya0, za = it ? za1 : za0;
        float xb = it ? xb1 : xb0, yb = it ? yb1 : yb0, zb = it ? zb1 : zb0;

        // ---- features: lane (c,g) -> channels 8g..8g+7, points A, B ----
        short8 bfA0 = sample_frag(P, 0,      xa, ya, g8);
        short8 bfA1 = sample_frag(P, 131072, xa, za, g8);
        short8 bfA2 = sample_frag(P, 262144, ya, za, g8);
        short8 bfB0 = sample_frag(P, 0,      xb, yb, g8);
        short8 bfB1 = sample_frag(P, 131072, xb, zb, g8);
        short8 bfB2 = sample_frag(P, 262144, yb, zb, g8);

        // ---- layer1 rgb half (nt=8..15): fold rW2 immediately, vector accs ----
        f32x4 r0A4 = {0.f,0.f,0.f,0.f}, r1A4 = {0.f,0.f,0.f,0.f}, r2A4 = {0.f,0.f,0.f,0.f};
        f32x4 r0B4 = {0.f,0.f,0.f,0.f}, r1B4 = {0.f,0.f,0.f,0.f}, r2B4 = {0.f,0.f,0.f,0.f};
        #pragma unroll 4
        for (int nt = 8; nt < 16; ++nt) {
            const ushort* wp = W1L + nt * 1536 + lane * 8;
            short8 a0 = *(const short8*)(wp);
            short8 a1 = *(const short8*)(wp + 512);
            short8 a2 = *(const short8*)(wp + 1024);
            f32x4 accA = {0.f,0.f,0.f,0.f}, accB = {0.f,0.f,0.f,0.f};
            accA = MFMA(a0, bfA0, accA); accB = MFMA(a0, bfB0, accB);
            accA = MFMA(a1, bfA1, accA); accB = MFMA(a1, bfB1, accB);
            accA = MFMA(a2, bfA2, accA); accB = MFMA(a2, bfB2, accB);
            int jo = (nt - 8) * 16 + 4 * g;
            f32x4 bb = *(const f32x4*)(Cl + 128 + jo);
            f32x4 w0 = *(const f32x4*)(Cl + 512 + jo);
            f32x4 w1 = *(const f32x4*)(Cl + 640 + jo);
            f32x4 w2 = *(const f32x4*)(Cl + 768 + jo);
            f32x4 vA = relu4(accA + bb);
            f32x4 vB = relu4(accB + bb);
            r0A4 += w0 * vA; r0B4 += w0 * vB;
            r1A4 += w1 * vA; r1B4 += w1 * vB;
            r2A4 += w2 * vA; r2B4 += w2 * vB;
        }
        // rgb heads now (kills racc early)
        {
            float v0 = hsum4(r0A4), v1 = hsum4(r1A4), v2 = hsum4(r2A4);
            v0 += __shfl_xor(v0, 16, 64); v0 += __shfl_xor(v0, 32, 64);
            v1 += __shfl_xor(v1, 16, 64); v1 += __shfl_xor(v1, 32, 64);
            v2 += __shfl_xor(v2, 16, 64); v2 += __shfl_xor(v2, 32, 64);
            if (g == 0) {
                rgb_out[ptA * 3 + 0] = 1.0f / (1.0f + expf(-(v0 + rb0)));
                rgb_out[ptA * 3 + 1] = 1.0f / (1.0f + expf(-(v1 + rb1v)));
                rgb_out[ptA * 3 + 2] = 1.0f / (1.0f + expf(-(v2 + rb2v)));
            }
        }
        {
            float v0 = hsum4(r0B4), v1 = hsum4(r1B4), v2 = hsum4(r2B4);
            v0 += __shfl_xor(v0, 16, 64); v0 += __shfl_xor(v0, 32, 64);
            v1 += __shfl_xor(v1, 16, 64); v1 += __shfl_xor(v1, 32, 64);
            v2 += __shfl_xor(v2, 16, 64); v2 += __shfl_xor(v2, 32, 64);
            if (g == 0) {
                rgb_out[ptB * 3 + 0] = 1.0f / (1.0f + expf(-(v0 + rb0)));
                rgb_out[ptB * 3 + 1] = 1.0f / (1.0f + expf(-(v1 + rb1v)));
                rgb_out[ptB * 3 + 2] = 1.0f / (1.0f + expf(-(v2 + rb2v)));
            }
        }

        // ---- layer1 density half (nt=0..7): A -> H, B -> named regs ----
        unsigned hB0a, hB0b, hB1a, hB1b, hB2a, hB2b, hB3a, hB3b;
        unsigned hB4a, hB4b, hB5a, hB5b, hB6a, hB6b, hB7a, hB7b;
        DNT(0, hB0a, hB0b) DNT(1, hB1a, hB1b) DNT(2, hB2a, hB2b) DNT(3, hB3a, hB3b)
        DNT(4, hB4a, hB4b) DNT(5, hB5a, hB5b) DNT(6, hB6a, hB6b) DNT(7, hB7a, hB7b)

        DSWALL;   // all A-writes issue before A-reads (same-wave LDS is in-order)
        short8 b2A0 = *(const short8*)(&H[c][g8]);
        short8 b2A1 = *(const short8*)(&H[c][32 + g8]);
        short8 b2A2 = *(const short8*)(&H[c][64 + g8]);
        short8 b2A3 = *(const short8*)(&H[c][96 + g8]);
        DSWALL;   // A-reads issue before B overwrites
        HWB(0, hB0a, hB0b) HWB(1, hB1a, hB1b) HWB(2, hB2a, hB2b) HWB(3, hB3a, hB3b)
        HWB(4, hB4a, hB4b) HWB(5, hB5a, hB5b) HWB(6, hB6a, hB6b) HWB(7, hB7a, hB7b)
        DSWALL;   // B-writes issue before B-reads
        short8 b2B0 = *(const short8*)(&H[c][g8]);
        short8 b2B1 = *(const short8*)(&H[c][32 + g8]);
        short8 b2B2 = *(const short8*)(&H[c][64 + g8]);
        short8 b2B3 = *(const short8*)(&H[c][96 + g8]);
        DSWALL;   // B-reads issue before next tile's A-writes
        // (no full memory clobber here: DSWALL alone orders the cross-tile H
        // reuse; global gather loads of the next tile may now hoist above.)

        // ---- layer2 + density fold: vector accumulators ----
        f32x4 dA4 = {0.f,0.f,0.f,0.f}, dB4 = {0.f,0.f,0.f,0.f};
        #pragma unroll 2
        for (int nt2 = 0; nt2 < 8; ++nt2) {
            const ushort* wp = W2L + nt2 * 2048 + lane * 8;
            short8 a0 = *(const short8*)(wp);
            short8 a1 = *(const short8*)(wp + 512);
            short8 a2 = *(const short8*)(wp + 1024);
            short8 a3 = *(const short8*)(wp + 1536);
            f32x4 accA = {0.f,0.f,0.f,0.f}, accB = {0.f,0.f,0.f,0.f};
            accA = MFMA(a0, b2A0, accA); accB = MFMA(a0, b2B0, accB);
            accA = MFMA(a1, b2A1, accA); accB = MFMA(a1, b2B1, accB);
            accA = MFMA(a2, b2A2, accA); accB = MFMA(a2, b2B2, accB);
            accA = MFMA(a3, b2A3, accA); accB = MFMA(a3, b2B3, accB);
            f32x4 bb = *(const f32x4*)(Cl + 256 + nt2 * 16 + 4 * g);
            f32x4 w3 = *(const f32x4*)(Cl + 384 + nt2 * 16 + 4 * g);
            dA4 += w3 * relu4(accA + bb);
            dB4 += w3 * relu4(accB + bb);
        }

        // ---- density heads ----
        {
            float v = hsum4(dA4);
            v += __shfl_xor(v, 16, 64); v += __shfl_xor(v, 32, 64); v += b3;
            float sp = fmaxf(v, 0.0f) + log1pf(expf(-fabsf(v)));
            if (g == 0) den_out[ptA] = sp;
        }
        {
            float v = hsum4(dB4);
            v += __shfl_xor(v, 16, 64); v += __shfl_xor(v, 32, 64); v += b3;
            float sp = fmaxf(v, 0.0f) + log1pf(expf(-fabsf(v)));
            if (g == 0) den_out[ptB] = sp;
        }
    }
}

extern "C" void kernel_launch(void* const* d_in, const int* in_sizes, int n_in,
                              void* d_out, int out_size, void* d_ws, size_t ws_size,
                              hipStream_t stream) {
    const float* points = (const float*)d_in[0];
    const float* planes = (const float*)d_in[1];
    const float* dW1    = (const float*)d_in[2];
    const float* db1    = (const float*)d_in[3];
    const float* dW2    = (const float*)d_in[4];
    const float* db2    = (const float*)d_in[5];
    const float* dW3    = (const float*)d_in[6];
    const float* db3    = (const float*)d_in[7];
    const float* rW1    = (const float*)d_in[8];
    const float* rb1    = (const float*)d_in[9];
    const float* rW2    = (const float*)d_in[10];
    const float* rb2    = (const float*)d_in[11];

    float* out     = (float*)d_out;
    float* rgb_out = out;                 // 3*NPTS floats
    float* den_out = out + 3 * NPTS;      // NPTS floats
    float* ws      = (float*)d_ws;

    prepass<<<1536, 256, 0, stream>>>(planes, dW1, rW1, dW2, db1, rb1,
                                      db2, dW3, rW2, ws);
    nerf_mfma<<<1024, 1024, 0, stream>>>(points, ws, db3, rb2, rgb_out, den_out);
}